// Round 3
// baseline (8762.180 us; speedup 1.0000x reference)
//
#include <hip/hip_runtime.h>
#include <stdint.h>

#define BM 128
#define BN 128
#define BK 64

typedef __bf16 bf16x8 __attribute__((ext_vector_type(8)));
typedef float f32x4 __attribute__((ext_vector_type(4)));

__device__ __forceinline__ float bf2f(uint16_t u) {
  union { uint32_t u32; float f; } x; x.u32 = ((uint32_t)u) << 16; return x.f;
}
// round-to-nearest-even f32 -> bf16 (finite values only)
__device__ __forceinline__ uint16_t f2bf(float f) {
  uint32_t x = __float_as_uint(f);
  uint32_t r = (x + 0x7FFFu + ((x >> 16) & 1u)) >> 16;
  return (uint16_t)r;
}

// C(BMxBN at m0,n0) += A(MxK row-major bf16) * Bt(NxK row-major bf16)^T
// Register staging (uint4 global load -> uint4 LDS store).
// LDS: ldsA[m][k] 128x64, ldsB[n][k] 128x64; all frag reads ds_read_b128.
// Wave (wr,wc) owns a 64x64 quadrant; 4x4 grid of 16x16x32 MFMA tiles.
// Layouts (learn_hip m89/m91): A-frag A[m=lane&15][k=(lane>>4)*8+j],
// B-frag Bt[n=lane&15][k=(lane>>4)*8+j], C/D col=lane&15, row=(lane>>4)*4+reg.
__device__ __forceinline__ void gemm_tile(
    const uint16_t* __restrict__ A, int ldA,
    const uint16_t* __restrict__ Bt, int ldB,
    int m0, int n0, int K,
    uint16_t* ldsA, uint16_t* ldsB, f32x4 acc[4][4])
{
  const int t  = threadIdx.x;
  const int ln = t & 63;
  const int wv = t >> 6;
  const int wr = wv >> 1, wc = wv & 1;

  // thread t stages row (t>>3)+32c, 16B chunk at col (t&7)*8.
  // LDS elem offset = ((t>>3)+32c)*64 + (t&7)*8 = 8t + 2048c.
  const uint16_t* ga = A  + (size_t)(m0 + (t >> 3)) * ldA + ((t & 7) << 3);
  const uint16_t* gb = Bt + (size_t)(n0 + (t >> 3)) * ldB + ((t & 7) << 3);
  uint16_t* la = ldsA + (t << 3);
  uint16_t* lb = ldsB + (t << 3);

  for (int kt = 0; kt < K; kt += BK) {
    uint4 va[4], vb[4];
#pragma unroll
    for (int c = 0; c < 4; ++c) {
      va[c] = *(const uint4*)(ga + (size_t)(c * 32) * ldA);
      vb[c] = *(const uint4*)(gb + (size_t)(c * 32) * ldB);
    }
    ga += BK; gb += BK;
    __syncthreads();            // previous tile's readers done
#pragma unroll
    for (int c = 0; c < 4; ++c) {
      *(uint4*)(la + c * 2048) = va[c];
      *(uint4*)(lb + c * 2048) = vb[c];
    }
    __syncthreads();            // staging visible

#pragma unroll
    for (int kk = 0; kk < 2; ++kk) {
      const int kof = (kk << 5) + ((ln >> 4) << 3);
      bf16x8 af[4], bfr[4];
#pragma unroll
      for (int mt = 0; mt < 4; ++mt)
        af[mt] = *(const bf16x8*)&ldsA[((wr << 6) + (mt << 4) + (ln & 15)) * BK + kof];
#pragma unroll
      for (int nt = 0; nt < 4; ++nt)
        bfr[nt] = *(const bf16x8*)&ldsB[((wc << 6) + (nt << 4) + (ln & 15)) * BK + kof];
#pragma unroll
      for (int mt = 0; mt < 4; ++mt)
#pragma unroll
        for (int nt = 0; nt < 4; ++nt)
          acc[mt][nt] = __builtin_amdgcn_mfma_f32_16x16x32_bf16(
              af[mt], bfr[nt], acc[mt][nt], 0, 0, 0);
    }
  }
}

// One Jacobi relaxation step, 3 GEMMs fused in one 640-block grid.
//  blocks   0..127 (mode 0): pre0 = s1 @ W0^T            (Bt = W0b native)
//  blocks 128..383 (mode 1): pre1 = s2 @ W1^T + s0 @ W0  (pass1 W1b native, pass2 W0Tb)
//  blocks 384..639 (mode 2): pre2 = s1 @ W1              (Bt = W1Tb)
// fp32 masters (inside d_out) updated in place; bf16 shadows double-buffered.
__global__ void step_kernel(
    const uint16_t* __restrict__ s0b_c, const uint16_t* __restrict__ s1b_c,
    const uint16_t* __restrict__ s2b_c,
    uint16_t* __restrict__ s0b_n, uint16_t* __restrict__ s1b_n,
    uint16_t* __restrict__ s2b_n,
    const uint16_t* __restrict__ W0b, const uint16_t* __restrict__ W0Tb,
    const uint16_t* __restrict__ W1b, const uint16_t* __restrict__ W1Tb,
    const float* __restrict__ b0, const float* __restrict__ b1,
    const float* __restrict__ c2f,
    float* __restrict__ s0f, float* __restrict__ s1f, float* __restrict__ s2f)
{
  __shared__ uint16_t ldsA[BM * BK];
  __shared__ uint16_t ldsB[BN * BK];

  f32x4 acc[4][4];
  const f32x4 z = {0.f, 0.f, 0.f, 0.f};
#pragma unroll
  for (int i = 0; i < 4; ++i)
#pragma unroll
    for (int j = 0; j < 4; ++j) acc[i][j] = z;

  const int b = blockIdx.x;
  int mode, bm, bn;
  if (b < 128) {
    mode = 0; bm = b >> 3; bn = b & 7;
    gemm_tile(s1b_c, 2048, W0b, 2048, bm * BM, bn * BN, 2048, ldsA, ldsB, acc);
  } else if (b < 384) {
    mode = 1; const int u = b - 128; bm = u >> 4; bn = u & 15;
    gemm_tile(s2b_c, 2048, W1b, 2048, bm * BM, bn * BN, 2048, ldsA, ldsB, acc);
    gemm_tile(s0b_c, 1024, W0Tb, 1024, bm * BM, bn * BN, 1024, ldsA, ldsB, acc);
  } else {
    mode = 2; const int u = b - 384; bm = u >> 4; bn = u & 15;
    gemm_tile(s1b_c, 2048, W1Tb, 2048, bm * BM, bn * BN, 2048, ldsA, ldsB, acc);
  }

  const int t = threadIdx.x, wv = t >> 6, ln = t & 63;
  const int wr = wv >> 1, wc = wv & 1;
  const int rb = (ln >> 4) << 2, cc = ln & 15;
  const int m0 = bm * BM, n0 = bn * BN;

#pragma unroll
  for (int mt = 0; mt < 4; ++mt) {
#pragma unroll
    for (int nt = 0; nt < 4; ++nt) {
      const int gn = n0 + (wc << 6) + (nt << 4) + cc;
      float add = 0.f;
      if (mode == 0) add = b0[gn];
      else if (mode == 1) add = b1[gn];
#pragma unroll
      for (int r = 0; r < 4; ++r) {
        const int gm = m0 + (wr << 6) + (mt << 4) + rb + r;
        const float pre = acc[mt][nt][r];
        if (mode == 0) {
          const size_t ix = (size_t)gm * 1024 + gn;
          float nv = 0.8f * s0f[ix] + 0.2f * (pre + add);
          nv = fminf(fmaxf(nv, 0.f), 1.f);
          s0f[ix] = nv;
          s0b_n[ix] = f2bf(nv);
        } else if (mode == 1) {
          const size_t ix = (size_t)gm * 2048 + gn;
          float nv = 0.8f * s1f[ix] + 0.2f * (pre + add);
          nv = fminf(fmaxf(nv, 0.f), 1.f);
          s1f[ix] = nv;
          s1b_n[ix] = f2bf(nv);
        } else {
          const size_t ix = (size_t)gm * 2048 + gn;
          float nv = 0.8f * s2f[ix] + 0.2f * (pre + c2f[ix]);
          nv = fminf(fmaxf(nv, 0.f), 1.f);
          s2f[ix] = nv;
          s2b_n[ix] = f2bf(nv);
        }
      }
    }
  }
}

// c2 = data @ W2^T + b2 (step-invariant), fp32 result.
__global__ void c2_kernel(const uint16_t* __restrict__ datab,
                          const uint16_t* __restrict__ W2b,
                          const float* __restrict__ b2,
                          float* __restrict__ c2f)
{
  __shared__ uint16_t ldsA[BM * BK];
  __shared__ uint16_t ldsB[BN * BK];
  f32x4 acc[4][4];
  const f32x4 z = {0.f, 0.f, 0.f, 0.f};
#pragma unroll
  for (int i = 0; i < 4; ++i)
#pragma unroll
    for (int j = 0; j < 4; ++j) acc[i][j] = z;

  const int bm = blockIdx.x >> 4, bn = blockIdx.x & 15;
  gemm_tile(datab, 2048, W2b, 2048, bm * BM, bn * BN, 2048, ldsA, ldsB, acc);

  const int t = threadIdx.x, wv = t >> 6, ln = t & 63;
  const int wr = wv >> 1, wc = wv & 1;
  const int rb = (ln >> 4) << 2, cc = ln & 15;
  const int m0 = bm * BM, n0 = bn * BN;
#pragma unroll
  for (int mt = 0; mt < 4; ++mt)
#pragma unroll
    for (int nt = 0; nt < 4; ++nt) {
      const int gn = n0 + (wc << 6) + (nt << 4) + cc;
      const float bb = b2[gn];
#pragma unroll
      for (int r = 0; r < 4; ++r) {
        const int gm = m0 + (wr << 6) + (mt << 4) + rb + r;
        c2f[(size_t)gm * 2048 + gn] = acc[mt][nt][r] + bb;
      }
    }
}

// fp32 -> bf16 straight convert, 4 elems/thread. n must be multiple of 1024.
__global__ void conv_k(const float* __restrict__ src, uint16_t* __restrict__ dst)
{
  const size_t i4 = ((size_t)blockIdx.x * 256 + threadIdx.x) << 2;
  const float4 v = *(const float4*)(src + i4);
  ushort4 o;
  o.x = f2bf(v.x); o.y = f2bf(v.y); o.z = f2bf(v.z); o.w = f2bf(v.w);
  *(ushort4*)(dst + i4) = o;
}

// fp32 -> bf16 transposed: dst[c*ldD + r] = bf16(src[r*ldS + c]).
// grid(C/32, R/32), block(32,32).
__global__ void convT_k(const float* __restrict__ src, uint16_t* __restrict__ dst,
                        int ldS, int ldD)
{
  __shared__ uint16_t tile[32][33];
  const int r0 = blockIdx.y * 32, c0 = blockIdx.x * 32;
  tile[threadIdx.y][threadIdx.x] =
      f2bf(src[(size_t)(r0 + threadIdx.y) * ldS + c0 + threadIdx.x]);
  __syncthreads();
  dst[(size_t)(c0 + threadIdx.y) * ldD + r0 + threadIdx.x] = tile[threadIdx.x][threadIdx.y];
}

// fp32 input -> fp32 master (in d_out) + bf16 shadow. 4 elems/thread.
__global__ void init_state(const float* __restrict__ in,
                           float* __restrict__ sf, uint16_t* __restrict__ sb)
{
  const size_t i4 = ((size_t)blockIdx.x * 256 + threadIdx.x) << 2;
  const float4 v = *(const float4*)(in + i4);
  *(float4*)(sf + i4) = v;
  ushort4 o;
  o.x = f2bf(v.x); o.y = f2bf(v.y); o.z = f2bf(v.z); o.w = f2bf(v.w);
  *(ushort4*)(sb + i4) = o;
}

extern "C" void kernel_launch(void* const* d_in, const int* in_sizes, int n_in,
                              void* d_out, int out_size, void* d_ws, size_t ws_size,
                              hipStream_t stream) {
  // Reference dtypes are float32 throughout (setup_inputs uses jnp.float32).
  const float* s0   = (const float*)d_in[0];
  const float* s1   = (const float*)d_in[1];
  const float* s2   = (const float*)d_in[2];
  const float* data = (const float*)d_in[3];
  const float* W0   = (const float*)d_in[4];
  const float* b0   = (const float*)d_in[5];
  const float* W1   = (const float*)d_in[6];
  const float* b1   = (const float*)d_in[7];
  const float* W2   = (const float*)d_in[8];
  const float* b2   = (const float*)d_in[9];

  // fp32 masters live directly in d_out: [s0 | s1 | s2] = 2M + 4M + 4M floats.
  float* s0f = (float*)d_out;
  float* s1f = s0f + 2048ull * 1024;
  float* s2f = s1f + 2048ull * 2048;

  char* ws = (char*)d_ws;
  size_t off = 0;
  auto alloc = [&](size_t bytes) -> char* {
    char* p = ws + off; off += (bytes + 255) & ~(size_t)255; return p;
  };
  uint16_t* W0b    = (uint16_t*)alloc(1024ull * 2048 * 2); // W0 native, bf16
  uint16_t* W0Tb   = (uint16_t*)alloc(2048ull * 1024 * 2); // W0T[n][k]=W0[k][n]
  uint16_t* W1b    = (uint16_t*)alloc(2048ull * 2048 * 2); // W1 native, bf16
  uint16_t* W1Tb   = (uint16_t*)alloc(2048ull * 2048 * 2); // W1T[n][k]=W1[k][n]
  float*    c2f    = (float*)   alloc(2048ull * 2048 * 4); // data@W2^T + b2, fp32
  uint16_t* s0b[2] = { (uint16_t*)alloc(2048ull * 1024 * 2),
                       (uint16_t*)alloc(2048ull * 1024 * 2) };
  uint16_t* s1b[2] = { (uint16_t*)alloc(2048ull * 2048 * 2),
                       (uint16_t*)alloc(2048ull * 2048 * 2) };
  uint16_t* s2b[2] = { (uint16_t*)alloc(2048ull * 2048 * 2),
                       (uint16_t*)alloc(2048ull * 2048 * 2) };
  (void)ws_size; (void)in_sizes; (void)n_in; (void)out_size;

  // --- one-time weight prep (fp32 -> bf16) ---
  conv_k<<<1024 * 2048 / 1024, 256, 0, stream>>>(W0, W0b);
  conv_k<<<2048 * 2048 / 1024, 256, 0, stream>>>(W1, W1b);
  dim3 tb(32, 32);
  convT_k<<<dim3(64, 32), tb, 0, stream>>>(W0, W0Tb, 2048, 1024);
  convT_k<<<dim3(64, 64), tb, 0, stream>>>(W1, W1Tb, 2048, 2048);
  // data, W2 -> bf16 into step-"next" shadow buffers (fully overwritten by step 0
  // epilogue before any read of them in step 1 — safe temps).
  conv_k<<<2048 * 2048 / 1024, 256, 0, stream>>>(data, s1b[1]);
  conv_k<<<2048 * 2048 / 1024, 256, 0, stream>>>(W2, s2b[1]);
  c2_kernel<<<256, 256, 0, stream>>>(s1b[1], s2b[1], b2, c2f);

  // --- state init: fp32 masters (in d_out) + bf16 shadows ---
  init_state<<<2048 * 1024 / 1024, 256, 0, stream>>>(s0, s0f, s0b[0]);
  init_state<<<2048 * 2048 / 1024, 256, 0, stream>>>(s1, s1f, s1b[0]);
  init_state<<<2048 * 2048 / 1024, 256, 0, stream>>>(s2, s2f, s2b[0]);

  // --- 30 Jacobi relaxation steps, double-buffered bf16 shadows ---
  for (int it = 0; it < 30; ++it) {
    const int c = it & 1, n = c ^ 1;
    step_kernel<<<640, 256, 0, stream>>>(
        s0b[c], s1b[c], s2b[c], s0b[n], s1b[n], s2b[n],
        W0b, W0Tb, W1b, W1Tb, b0, b1, c2f, s0f, s1f, s2f);
  }
  // masters already in d_out — no output kernel needed.
}

// Round 4
// 2442.164 us; speedup vs baseline: 3.5879x; 3.5879x over previous
//
#include <hip/hip_runtime.h>
#include <stdint.h>

#define BM 128
#define BN 128
#define BK 64

typedef __bf16 bf16x8 __attribute__((ext_vector_type(8)));
typedef float f32x4 __attribute__((ext_vector_type(4)));

__device__ __forceinline__ float bf2f(uint16_t u) {
  union { uint32_t u32; float f; } x; x.u32 = ((uint32_t)u) << 16; return x.f;
}
// round-to-nearest-even f32 -> bf16 (finite values only)
__device__ __forceinline__ uint16_t f2bf(float f) {
  uint32_t x = __float_as_uint(f);
  uint32_t r = (x + 0x7FFFu + ((x >> 16) & 1u)) >> 16;
  return (uint16_t)r;
}

// async global->LDS, 16B per lane. LDS dest is wave-uniform base + lane*16B;
// our per-lane lds ptr (16B * t) is exactly lane-contiguous per wave.
__device__ __forceinline__ void gload_lds16(const uint16_t* g, uint16_t* l) {
  __builtin_amdgcn_global_load_lds(
      (const __attribute__((address_space(1))) uint32_t*)g,
      (__attribute__((address_space(3))) uint32_t*)l, 16, 0, 0);
}

// C(BMxBN at m0,n0) += A(MxK row-major bf16) * Bt(NxK row-major bf16)^T
// Staging: global_load_lds width=16 (m97 path). LDS ldsA[m][kc] with XOR swizzle:
// LDS[row][slot] holds global 16B-chunk (slot ^ (row&7)) -> frag ds_read_b128
// spreads over all 32 banks (2-way aliasing = free) instead of 16-way on banks 0-3.
// Values at each logical (row,k) are unchanged -> bit-identical numerics.
// Wave (wr,wc) owns a 64x64 quadrant; 4x4 grid of 16x16x32 MFMA tiles.
__device__ __forceinline__ void gemm_tile(
    const uint16_t* __restrict__ A, int ldA,
    const uint16_t* __restrict__ Bt, int ldB,
    int m0, int n0, int K,
    uint16_t* ldsA, uint16_t* ldsB, f32x4 acc[4][4])
{
  const int t  = threadIdx.x;
  const int ln = t & 63;
  const int wv = t >> 6;
  const int wr = wv >> 1, wc = wv & 1;

  // thread t stages rows (t>>3)+32c; fetches global chunk gc=(t&7)^(row&7)
  // into LDS slot (t&7). (row+32c)&7 == row&7, so gc is loop-invariant.
  const int row = t >> 3;
  const int gc  = (t & 7) ^ (row & 7);
  const uint16_t* ga = A  + (size_t)(m0 + row) * ldA + (gc << 3);
  const uint16_t* gb = Bt + (size_t)(n0 + row) * ldB + (gc << 3);
  uint16_t* la = ldsA + (t << 3);   // 16B * t : lane-contiguous per wave
  uint16_t* lb = ldsB + (t << 3);

  for (int kt = 0; kt < K; kt += BK) {
    __syncthreads();               // previous tile's readers done
#pragma unroll
    for (int c = 0; c < 4; ++c) {
      gload_lds16(ga + (size_t)(c * 32) * ldA, la + c * 2048);
      gload_lds16(gb + (size_t)(c * 32) * ldB, lb + c * 2048);
    }
    ga += BK; gb += BK;
    __syncthreads();               // barrier drains vmcnt -> staging visible

#pragma unroll
    for (int kk = 0; kk < 2; ++kk) {
      const int kc = (kk << 2) + (ln >> 4);       // logical 16B chunk in K
      const int sw = (kc ^ (ln & 7)) << 3;        // swizzled elem offset (row&7==ln&7)
      bf16x8 af[4], bfr[4];
#pragma unroll
      for (int mt = 0; mt < 4; ++mt)
        af[mt] = *(const bf16x8*)&ldsA[((wr << 6) + (mt << 4) + (ln & 15)) * BK + sw];
#pragma unroll
      for (int nt = 0; nt < 4; ++nt)
        bfr[nt] = *(const bf16x8*)&ldsB[((wc << 6) + (nt << 4) + (ln & 15)) * BK + sw];
#pragma unroll
      for (int mt = 0; mt < 4; ++mt)
#pragma unroll
        for (int nt = 0; nt < 4; ++nt)
          acc[mt][nt] = __builtin_amdgcn_mfma_f32_16x16x32_bf16(
              af[mt], bfr[nt], acc[mt][nt], 0, 0, 0);
    }
  }
}

// One Jacobi relaxation step, 3 GEMMs fused in one 640-block grid.
// XCD-aware map: XCD x = b&7 owns bm in {2x, 2x+1} for ALL modes -> the XCD's
// A-panels (s1/s2/s0 rows, ~2.5 MB) are L2-resident and reused 16x across bn
// and across modes; B (weights) streams once per XCD from L3.
//  j<16  (mode 0): pre0 = s1 @ W0^T            (Bt = W0b native)
//  j<48  (mode 1): pre1 = s2 @ W1^T + s0 @ W0  (pass1 W1b native, pass2 W0Tb)
//  else  (mode 2): pre2 = s1 @ W1              (Bt = W1Tb)
// fp32 masters (in d_out) updated in place; bf16 shadows double-buffered.
__global__ void step_kernel(
    const uint16_t* __restrict__ s0b_c, const uint16_t* __restrict__ s1b_c,
    const uint16_t* __restrict__ s2b_c,
    uint16_t* __restrict__ s0b_n, uint16_t* __restrict__ s1b_n,
    uint16_t* __restrict__ s2b_n,
    const uint16_t* __restrict__ W0b, const uint16_t* __restrict__ W0Tb,
    const uint16_t* __restrict__ W1b, const uint16_t* __restrict__ W1Tb,
    const float* __restrict__ b0, const float* __restrict__ b1,
    const float* __restrict__ c2f,
    float* __restrict__ s0f, float* __restrict__ s1f, float* __restrict__ s2f)
{
  __shared__ uint16_t ldsA[BM * BK];
  __shared__ uint16_t ldsB[BN * BK];

  f32x4 acc[4][4];
  const f32x4 z = {0.f, 0.f, 0.f, 0.f};
#pragma unroll
  for (int i = 0; i < 4; ++i)
#pragma unroll
    for (int j = 0; j < 4; ++j) acc[i][j] = z;

  const int x = blockIdx.x & 7;    // XCD (dispatch round-robin heuristic)
  const int j = blockIdx.x >> 3;   // 0..79 within XCD
  int mode, bm, bn;
  if (j < 16) {
    mode = 0; bm = (x << 1) + (j >> 3); bn = j & 7;
    gemm_tile(s1b_c, 2048, W0b, 2048, bm * BM, bn * BN, 2048, ldsA, ldsB, acc);
  } else if (j < 48) {
    mode = 1; const int u = j - 16; bm = (x << 1) + (u >> 4); bn = u & 15;
    gemm_tile(s2b_c, 2048, W1b, 2048, bm * BM, bn * BN, 2048, ldsA, ldsB, acc);
    gemm_tile(s0b_c, 1024, W0Tb, 1024, bm * BM, bn * BN, 1024, ldsA, ldsB, acc);
  } else {
    mode = 2; const int u = j - 48; bm = (x << 1) + (u >> 4); bn = u & 15;
    gemm_tile(s1b_c, 2048, W1Tb, 2048, bm * BM, bn * BN, 2048, ldsA, ldsB, acc);
  }

  const int t = threadIdx.x, wv = t >> 6, ln = t & 63;
  const int wr = wv >> 1, wc = wv & 1;
  const int rb = (ln >> 4) << 2, cc = ln & 15;
  const int m0 = bm * BM, n0 = bn * BN;

#pragma unroll
  for (int mt = 0; mt < 4; ++mt) {
#pragma unroll
    for (int nt = 0; nt < 4; ++nt) {
      const int gn = n0 + (wc << 6) + (nt << 4) + cc;
      float add = 0.f;
      if (mode == 0) add = b0[gn];
      else if (mode == 1) add = b1[gn];
#pragma unroll
      for (int r = 0; r < 4; ++r) {
        const int gm = m0 + (wr << 6) + (mt << 4) + rb + r;
        const float pre = acc[mt][nt][r];
        if (mode == 0) {
          const size_t ix = (size_t)gm * 1024 + gn;
          float nv = 0.8f * s0f[ix] + 0.2f * (pre + add);
          nv = fminf(fmaxf(nv, 0.f), 1.f);
          s0f[ix] = nv;
          s0b_n[ix] = f2bf(nv);
        } else if (mode == 1) {
          const size_t ix = (size_t)gm * 2048 + gn;
          float nv = 0.8f * s1f[ix] + 0.2f * (pre + add);
          nv = fminf(fmaxf(nv, 0.f), 1.f);
          s1f[ix] = nv;
          s1b_n[ix] = f2bf(nv);
        } else {
          const size_t ix = (size_t)gm * 2048 + gn;
          float nv = 0.8f * s2f[ix] + 0.2f * (pre + c2f[ix]);
          nv = fminf(fmaxf(nv, 0.f), 1.f);
          s2f[ix] = nv;
          s2b_n[ix] = f2bf(nv);
        }
      }
    }
  }
}

// c2 = data @ W2^T + b2 (step-invariant), fp32 result.
__global__ void c2_kernel(const uint16_t* __restrict__ datab,
                          const uint16_t* __restrict__ W2b,
                          const float* __restrict__ b2,
                          float* __restrict__ c2f)
{
  __shared__ uint16_t ldsA[BM * BK];
  __shared__ uint16_t ldsB[BN * BK];
  f32x4 acc[4][4];
  const f32x4 z = {0.f, 0.f, 0.f, 0.f};
#pragma unroll
  for (int i = 0; i < 4; ++i)
#pragma unroll
    for (int j = 0; j < 4; ++j) acc[i][j] = z;

  const int bm = blockIdx.x >> 4, bn = blockIdx.x & 15;
  gemm_tile(datab, 2048, W2b, 2048, bm * BM, bn * BN, 2048, ldsA, ldsB, acc);

  const int t = threadIdx.x, wv = t >> 6, ln = t & 63;
  const int wr = wv >> 1, wc = wv & 1;
  const int rb = (ln >> 4) << 2, cc = ln & 15;
  const int m0 = bm * BM, n0 = bn * BN;
#pragma unroll
  for (int mt = 0; mt < 4; ++mt)
#pragma unroll
    for (int nt = 0; nt < 4; ++nt) {
      const int gn = n0 + (wc << 6) + (nt << 4) + cc;
      const float bb = b2[gn];
#pragma unroll
      for (int r = 0; r < 4; ++r) {
        const int gm = m0 + (wr << 6) + (mt << 4) + rb + r;
        c2f[(size_t)gm * 2048 + gn] = acc[mt][nt][r] + bb;
      }
    }
}

// fp32 -> bf16 straight convert, 4 elems/thread.
__global__ void conv_k(const float* __restrict__ src, uint16_t* __restrict__ dst)
{
  const size_t i4 = ((size_t)blockIdx.x * 256 + threadIdx.x) << 2;
  const float4 v = *(const float4*)(src + i4);
  ushort4 o;
  o.x = f2bf(v.x); o.y = f2bf(v.y); o.z = f2bf(v.z); o.w = f2bf(v.w);
  *(ushort4*)(dst + i4) = o;
}

// fp32 -> bf16 transposed: dst[c*ldD + r] = bf16(src[r*ldS + c]).
__global__ void convT_k(const float* __restrict__ src, uint16_t* __restrict__ dst,
                        int ldS, int ldD)
{
  __shared__ uint16_t tile[32][33];
  const int r0 = blockIdx.y * 32, c0 = blockIdx.x * 32;
  tile[threadIdx.y][threadIdx.x] =
      f2bf(src[(size_t)(r0 + threadIdx.y) * ldS + c0 + threadIdx.x]);
  __syncthreads();
  dst[(size_t)(c0 + threadIdx.y) * ldD + r0 + threadIdx.x] = tile[threadIdx.x][threadIdx.y];
}

// fp32 input -> fp32 master (in d_out) + bf16 shadow. 4 elems/thread.
__global__ void init_state(const float* __restrict__ in,
                           float* __restrict__ sf, uint16_t* __restrict__ sb)
{
  const size_t i4 = ((size_t)blockIdx.x * 256 + threadIdx.x) << 2;
  const float4 v = *(const float4*)(in + i4);
  *(float4*)(sf + i4) = v;
  ushort4 o;
  o.x = f2bf(v.x); o.y = f2bf(v.y); o.z = f2bf(v.z); o.w = f2bf(v.w);
  *(ushort4*)(sb + i4) = o;
}

extern "C" void kernel_launch(void* const* d_in, const int* in_sizes, int n_in,
                              void* d_out, int out_size, void* d_ws, size_t ws_size,
                              hipStream_t stream) {
  const float* s0   = (const float*)d_in[0];
  const float* s1   = (const float*)d_in[1];
  const float* s2   = (const float*)d_in[2];
  const float* data = (const float*)d_in[3];
  const float* W0   = (const float*)d_in[4];
  const float* b0   = (const float*)d_in[5];
  const float* W1   = (const float*)d_in[6];
  const float* b1   = (const float*)d_in[7];
  const float* W2   = (const float*)d_in[8];
  const float* b2   = (const float*)d_in[9];

  // fp32 masters live directly in d_out: [s0 | s1 | s2].
  float* s0f = (float*)d_out;
  float* s1f = s0f + 2048ull * 1024;
  float* s2f = s1f + 2048ull * 2048;

  char* ws = (char*)d_ws;
  size_t off = 0;
  auto alloc = [&](size_t bytes) -> char* {
    char* p = ws + off; off += (bytes + 255) & ~(size_t)255; return p;
  };
  uint16_t* W0b    = (uint16_t*)alloc(1024ull * 2048 * 2);
  uint16_t* W0Tb   = (uint16_t*)alloc(2048ull * 1024 * 2);
  uint16_t* W1b    = (uint16_t*)alloc(2048ull * 2048 * 2);
  uint16_t* W1Tb   = (uint16_t*)alloc(2048ull * 2048 * 2);
  float*    c2f    = (float*)   alloc(2048ull * 2048 * 4);
  uint16_t* s0b[2] = { (uint16_t*)alloc(2048ull * 1024 * 2),
                       (uint16_t*)alloc(2048ull * 1024 * 2) };
  uint16_t* s1b[2] = { (uint16_t*)alloc(2048ull * 2048 * 2),
                       (uint16_t*)alloc(2048ull * 2048 * 2) };
  uint16_t* s2b[2] = { (uint16_t*)alloc(2048ull * 2048 * 2),
                       (uint16_t*)alloc(2048ull * 2048 * 2) };
  (void)ws_size; (void)in_sizes; (void)n_in; (void)out_size;

  // --- one-time weight prep (fp32 -> bf16) ---
  conv_k<<<1024 * 2048 / 1024, 256, 0, stream>>>(W0, W0b);
  conv_k<<<2048 * 2048 / 1024, 256, 0, stream>>>(W1, W1b);
  dim3 tb(32, 32);
  convT_k<<<dim3(64, 32), tb, 0, stream>>>(W0, W0Tb, 2048, 1024);
  convT_k<<<dim3(64, 64), tb, 0, stream>>>(W1, W1Tb, 2048, 2048);
  // data, W2 -> bf16 into step-"next" shadow buffers (fully overwritten by step 0
  // epilogue before step 1 reads them — safe temps).
  conv_k<<<2048 * 2048 / 1024, 256, 0, stream>>>(data, s1b[1]);
  conv_k<<<2048 * 2048 / 1024, 256, 0, stream>>>(W2, s2b[1]);
  c2_kernel<<<256, 256, 0, stream>>>(s1b[1], s2b[1], b2, c2f);

  // --- state init: fp32 masters (in d_out) + bf16 shadows ---
  init_state<<<2048 * 1024 / 1024, 256, 0, stream>>>(s0, s0f, s0b[0]);
  init_state<<<2048 * 2048 / 1024, 256, 0, stream>>>(s1, s1f, s1b[0]);
  init_state<<<2048 * 2048 / 1024, 256, 0, stream>>>(s2, s2f, s2b[0]);

  // --- 30 Jacobi relaxation steps, double-buffered bf16 shadows ---
  for (int it = 0; it < 30; ++it) {
    const int c = it & 1, n = c ^ 1;
    step_kernel<<<640, 256, 0, stream>>>(
        s0b[c], s1b[c], s2b[c], s0b[n], s1b[n], s2b[n],
        W0b, W0Tb, W1b, W1Tb, b0, b1, c2f, s0f, s1f, s2f);
  }
  // masters already in d_out — no output kernel needed.
}